// Round 1
// baseline (925.241 us; speedup 1.0000x reference)
//
#include <hip/hip_runtime.h>
#include <math.h>

#define EPB 16
#define NTHREADS 256
#define INV_SQRT3f 0.57735026918962584f

__device__ __forceinline__ float silu_f(float x) {
    return x * (1.0f / (1.0f + __expf(-x)));
}

__global__ __launch_bounds__(NTHREADS)
void mpconv_fused(const float* __restrict__ edge_s,   // (E,64)
                  const float* __restrict__ edge_v,   // (E,64,3)
                  const float* __restrict__ attr_s,   // (E,1)
                  const float* __restrict__ attr_v,   // (E,3)
                  const float* __restrict__ W1,       // (64,128)
                  const float* __restrict__ b1,       // (128)
                  const float* __restrict__ W2,       // (128,128)
                  const float* __restrict__ b2,       // (128)
                  const float* __restrict__ Wg,       // (128,256)
                  const float* __restrict__ bg,       // (256)
                  const int*   __restrict__ recv,     // (E)
                  float* __restrict__ out)            // (N,512), pre-zeroed
{
    __shared__ float s_esT[64][20];    // edge_s transposed [k][e], padded
    __shared__ float s_h1T[128][20];   // h1 transposed [k][e]
    __shared__ float s_h2T[128][20];   // h2 transposed [k][e]
    __shared__ float s_as[EPB];
    __shared__ float s_av[EPB][3];
    __shared__ int   s_r[EPB];

    const int tid = threadIdx.x;
    const long e0 = (long)blockIdx.x * EPB;

    // ---- stage edge_s (transposed), attrs, receivers ----
    for (int idx = tid; idx < EPB * 64; idx += NTHREADS) {
        int e = idx >> 6, k = idx & 63;
        s_esT[k][e] = edge_s[(e0 + e) * 64 + k];
    }
    if (tid < EPB) {
        s_as[tid] = attr_s[e0 + tid];
        s_r[tid]  = recv[e0 + tid];
    }
    if (tid >= 64 && tid < 64 + EPB * 3) {
        int q = tid - 64; int e = q / 3, c = q - e * 3;
        s_av[e][c] = attr_v[(e0 + e) * 3 + c];
    }
    __syncthreads();

    const int j  = tid & 127;          // column for layers 1/2
    const int eg = (tid >> 7) << 3;    // edge-group base: 0 or 8

    // ---- layer 1: h1 = silu(es @ W1 + b1) ----
    {
        float acc[8];
        #pragma unroll
        for (int e = 0; e < 8; ++e) acc[e] = 0.0f;
        #pragma unroll 4
        for (int k = 0; k < 64; ++k) {
            float w  = W1[k * 128 + j];
            float4 a = *(const float4*)&s_esT[k][eg];
            float4 b = *(const float4*)&s_esT[k][eg + 4];
            acc[0] = fmaf(a.x, w, acc[0]);
            acc[1] = fmaf(a.y, w, acc[1]);
            acc[2] = fmaf(a.z, w, acc[2]);
            acc[3] = fmaf(a.w, w, acc[3]);
            acc[4] = fmaf(b.x, w, acc[4]);
            acc[5] = fmaf(b.y, w, acc[5]);
            acc[6] = fmaf(b.z, w, acc[6]);
            acc[7] = fmaf(b.w, w, acc[7]);
        }
        float bb = b1[j];
        float4 r0, r1;
        r0.x = silu_f(acc[0] + bb); r0.y = silu_f(acc[1] + bb);
        r0.z = silu_f(acc[2] + bb); r0.w = silu_f(acc[3] + bb);
        r1.x = silu_f(acc[4] + bb); r1.y = silu_f(acc[5] + bb);
        r1.z = silu_f(acc[6] + bb); r1.w = silu_f(acc[7] + bb);
        *(float4*)&s_h1T[j][eg]     = r0;
        *(float4*)&s_h1T[j][eg + 4] = r1;
    }
    __syncthreads();

    // ---- layer 2: h2 = silu(h1 @ W2 + b2) ----
    {
        float acc[8];
        #pragma unroll
        for (int e = 0; e < 8; ++e) acc[e] = 0.0f;
        #pragma unroll 4
        for (int k = 0; k < 128; ++k) {
            float w  = W2[k * 128 + j];
            float4 a = *(const float4*)&s_h1T[k][eg];
            float4 b = *(const float4*)&s_h1T[k][eg + 4];
            acc[0] = fmaf(a.x, w, acc[0]);
            acc[1] = fmaf(a.y, w, acc[1]);
            acc[2] = fmaf(a.z, w, acc[2]);
            acc[3] = fmaf(a.w, w, acc[3]);
            acc[4] = fmaf(b.x, w, acc[4]);
            acc[5] = fmaf(b.y, w, acc[5]);
            acc[6] = fmaf(b.z, w, acc[6]);
            acc[7] = fmaf(b.w, w, acc[7]);
        }
        float bb = b2[j];
        float4 r0, r1;
        r0.x = silu_f(acc[0] + bb); r0.y = silu_f(acc[1] + bb);
        r0.z = silu_f(acc[2] + bb); r0.w = silu_f(acc[3] + bb);
        r1.x = silu_f(acc[4] + bb); r1.y = silu_f(acc[5] + bb);
        r1.z = silu_f(acc[6] + bb); r1.w = silu_f(acc[7] + bb);
        *(float4*)&s_h2T[j][eg]     = r0;
        *(float4*)&s_h2T[j][eg + 4] = r1;
    }
    __syncthreads();

    // ---- layer 3: gate col tid for all 16 edges; fold 1/sqrt(16)=0.25 ----
    float g[EPB];
    {
        float acc[16];
        #pragma unroll
        for (int e = 0; e < 16; ++e) acc[e] = 0.0f;
        #pragma unroll 2
        for (int k = 0; k < 128; ++k) {
            float w = Wg[k * 256 + tid];
            float4 a0 = *(const float4*)&s_h2T[k][0];
            float4 a1 = *(const float4*)&s_h2T[k][4];
            float4 a2 = *(const float4*)&s_h2T[k][8];
            float4 a3 = *(const float4*)&s_h2T[k][12];
            acc[0]  = fmaf(a0.x, w, acc[0]);
            acc[1]  = fmaf(a0.y, w, acc[1]);
            acc[2]  = fmaf(a0.z, w, acc[2]);
            acc[3]  = fmaf(a0.w, w, acc[3]);
            acc[4]  = fmaf(a1.x, w, acc[4]);
            acc[5]  = fmaf(a1.y, w, acc[5]);
            acc[6]  = fmaf(a1.z, w, acc[6]);
            acc[7]  = fmaf(a1.w, w, acc[7]);
            acc[8]  = fmaf(a2.x, w, acc[8]);
            acc[9]  = fmaf(a2.y, w, acc[9]);
            acc[10] = fmaf(a2.z, w, acc[10]);
            acc[11] = fmaf(a2.w, w, acc[11]);
            acc[12] = fmaf(a3.x, w, acc[12]);
            acc[13] = fmaf(a3.y, w, acc[13]);
            acc[14] = fmaf(a3.z, w, acc[14]);
            acc[15] = fmaf(a3.w, w, acc[15]);
        }
        float bb = bg[tid];
        #pragma unroll
        for (int e = 0; e < 16; ++e) g[e] = (acc[e] + bb) * 0.25f;
    }
    // no sync needed: message phase reads only s_esT/s_as/s_av/s_r (stable)

    // ---- messages + atomic scatter ----
    if (tid < 128) {
        // m0 column j=tid: g0 = gate[:, tid]
        const int jj = tid;
        #pragma unroll 4
        for (int e = 0; e < EPB; ++e) {
            float val;
            if (jj < 64) {
                val = s_esT[jj][e] * s_as[e];
            } else {
                const float* ev = &edge_v[((e0 + e) * 64 + (jj - 64)) * 3];
                val = (ev[0] * s_av[e][0] + ev[1] * s_av[e][1] + ev[2] * s_av[e][2]) * INV_SQRT3f;
            }
            atomicAdd(&out[(long)s_r[e] * 512 + jj], val * g[e]);
        }
    } else {
        // m1 row i=tid-128 (3 components): g1 = gate[:, 128+i]
        const int i = tid - 128;
        #pragma unroll 4
        for (int e = 0; e < EPB; ++e) {
            float mx, my, mz;
            if (i < 64) {
                float es = s_esT[i][e];
                mx = es * s_av[e][0];
                my = es * s_av[e][1];
                mz = es * s_av[e][2];
            } else {
                const float* ev = &edge_v[((e0 + e) * 64 + (i - 64)) * 3];
                float as = s_as[e];
                mx = ev[0] * as;
                my = ev[1] * as;
                mz = ev[2] * as;
            }
            float* o = &out[(long)s_r[e] * 512 + 128 + i * 3];
            atomicAdd(o + 0, mx * g[e]);
            atomicAdd(o + 1, my * g[e]);
            atomicAdd(o + 2, mz * g[e]);
        }
    }
}

extern "C" void kernel_launch(void* const* d_in, const int* in_sizes, int n_in,
                              void* d_out, int out_size, void* d_ws, size_t ws_size,
                              hipStream_t stream) {
    const float* edge_s = (const float*)d_in[0];
    const float* edge_v = (const float*)d_in[1];
    const float* attr_s = (const float*)d_in[2];
    const float* attr_v = (const float*)d_in[3];
    const float* W1     = (const float*)d_in[4];
    const float* b1     = (const float*)d_in[5];
    const float* W2     = (const float*)d_in[6];
    const float* b2     = (const float*)d_in[7];
    const float* Wg     = (const float*)d_in[8];
    const float* bg     = (const float*)d_in[9];
    const int*   recv   = (const int*)d_in[10];

    const int E = in_sizes[0] / 64;          // 160000
    const int nblocks = E / EPB;             // 10000

    hipMemsetAsync(d_out, 0, (size_t)out_size * sizeof(float), stream);
    mpconv_fused<<<nblocks, NTHREADS, 0, stream>>>(
        edge_s, edge_v, attr_s, attr_v, W1, b1, W2, b2, Wg, bg, recv,
        (float*)d_out);
}

// Round 5
// 637.011 us; speedup vs baseline: 1.4525x; 1.4525x over previous
//
#include <hip/hip_runtime.h>
#include <math.h>

#define EPB 16
#define NTHREADS 256
#define SCAN_T 1024
#define MAX_NODES_SCAN 10240
#define INV_SQRT3f 0.57735026918962584f

__device__ __forceinline__ float silu_f(float x) {
    return x * (1.0f / (1.0f + __expf(-x)));
}

// ============================================================
// Per-edge MLP -> gate (256 f32 per edge, 0.25 folded)
// ============================================================
__global__ __launch_bounds__(NTHREADS)
void mlp_gate(const float* __restrict__ edge_s,   // (E,64)
              const float* __restrict__ W1,       // (64,128)
              const float* __restrict__ b1,       // (128)
              const float* __restrict__ W2,       // (128,128)
              const float* __restrict__ b2,       // (128)
              const float* __restrict__ Wg,       // (128,256)
              const float* __restrict__ bg,       // (256)
              float* __restrict__ gate_out)       // (E,256)
{
    __shared__ float s_esT[64][20];
    __shared__ float s_h1T[128][20];
    __shared__ float s_h2T[128][20];

    const int tid = threadIdx.x;
    const long e0 = (long)blockIdx.x * EPB;

    for (int idx = tid; idx < EPB * 64; idx += NTHREADS) {
        int e = idx >> 6, k = idx & 63;
        s_esT[k][e] = edge_s[(e0 + e) * 64 + k];
    }
    __syncthreads();

    const int j  = tid & 127;
    const int eg = (tid >> 7) << 3;

    // layer 1
    {
        float acc[8];
        #pragma unroll
        for (int e = 0; e < 8; ++e) acc[e] = 0.0f;
        #pragma unroll 4
        for (int k = 0; k < 64; ++k) {
            float w  = W1[k * 128 + j];
            float4 a = *(const float4*)&s_esT[k][eg];
            float4 b = *(const float4*)&s_esT[k][eg + 4];
            acc[0] = fmaf(a.x, w, acc[0]); acc[1] = fmaf(a.y, w, acc[1]);
            acc[2] = fmaf(a.z, w, acc[2]); acc[3] = fmaf(a.w, w, acc[3]);
            acc[4] = fmaf(b.x, w, acc[4]); acc[5] = fmaf(b.y, w, acc[5]);
            acc[6] = fmaf(b.z, w, acc[6]); acc[7] = fmaf(b.w, w, acc[7]);
        }
        float bb = b1[j];
        float4 r0, r1;
        r0.x = silu_f(acc[0] + bb); r0.y = silu_f(acc[1] + bb);
        r0.z = silu_f(acc[2] + bb); r0.w = silu_f(acc[3] + bb);
        r1.x = silu_f(acc[4] + bb); r1.y = silu_f(acc[5] + bb);
        r1.z = silu_f(acc[6] + bb); r1.w = silu_f(acc[7] + bb);
        *(float4*)&s_h1T[j][eg]     = r0;
        *(float4*)&s_h1T[j][eg + 4] = r1;
    }
    __syncthreads();

    // layer 2
    {
        float acc[8];
        #pragma unroll
        for (int e = 0; e < 8; ++e) acc[e] = 0.0f;
        #pragma unroll 4
        for (int k = 0; k < 128; ++k) {
            float w  = W2[k * 128 + j];
            float4 a = *(const float4*)&s_h1T[k][eg];
            float4 b = *(const float4*)&s_h1T[k][eg + 4];
            acc[0] = fmaf(a.x, w, acc[0]); acc[1] = fmaf(a.y, w, acc[1]);
            acc[2] = fmaf(a.z, w, acc[2]); acc[3] = fmaf(a.w, w, acc[3]);
            acc[4] = fmaf(b.x, w, acc[4]); acc[5] = fmaf(b.y, w, acc[5]);
            acc[6] = fmaf(b.z, w, acc[6]); acc[7] = fmaf(b.w, w, acc[7]);
        }
        float bb = b2[j];
        float4 r0, r1;
        r0.x = silu_f(acc[0] + bb); r0.y = silu_f(acc[1] + bb);
        r0.z = silu_f(acc[2] + bb); r0.w = silu_f(acc[3] + bb);
        r1.x = silu_f(acc[4] + bb); r1.y = silu_f(acc[5] + bb);
        r1.z = silu_f(acc[6] + bb); r1.w = silu_f(acc[7] + bb);
        *(float4*)&s_h2T[j][eg]     = r0;
        *(float4*)&s_h2T[j][eg + 4] = r1;
    }
    __syncthreads();

    // layer 3: gate column tid for all 16 edges; fold 1/sqrt(16)=0.25
    {
        float acc[16];
        #pragma unroll
        for (int e = 0; e < 16; ++e) acc[e] = 0.0f;
        #pragma unroll 2
        for (int k = 0; k < 128; ++k) {
            float w = Wg[k * 256 + tid];
            float4 a0 = *(const float4*)&s_h2T[k][0];
            float4 a1 = *(const float4*)&s_h2T[k][4];
            float4 a2 = *(const float4*)&s_h2T[k][8];
            float4 a3 = *(const float4*)&s_h2T[k][12];
            acc[0]  = fmaf(a0.x, w, acc[0]);  acc[1]  = fmaf(a0.y, w, acc[1]);
            acc[2]  = fmaf(a0.z, w, acc[2]);  acc[3]  = fmaf(a0.w, w, acc[3]);
            acc[4]  = fmaf(a1.x, w, acc[4]);  acc[5]  = fmaf(a1.y, w, acc[5]);
            acc[6]  = fmaf(a1.z, w, acc[6]);  acc[7]  = fmaf(a1.w, w, acc[7]);
            acc[8]  = fmaf(a2.x, w, acc[8]);  acc[9]  = fmaf(a2.y, w, acc[9]);
            acc[10] = fmaf(a2.z, w, acc[10]); acc[11] = fmaf(a2.w, w, acc[11]);
            acc[12] = fmaf(a3.x, w, acc[12]); acc[13] = fmaf(a3.y, w, acc[13]);
            acc[14] = fmaf(a3.z, w, acc[14]); acc[15] = fmaf(a3.w, w, acc[15]);
        }
        float bb = bg[tid];
        #pragma unroll
        for (int e = 0; e < 16; ++e)
            gate_out[(e0 + e) * 256 + tid] = (acc[e] + bb) * 0.25f;
    }
}

// ============================================================
// CSR build
// ============================================================
__global__ void csr_hist(const int* __restrict__ recv, int* __restrict__ counts, int E) {
    int e = blockIdx.x * 256 + threadIdx.x;
    if (e < E) atomicAdd(&counts[recv[e]], 1);
}

__global__ __launch_bounds__(SCAN_T)
void csr_scan(const int* __restrict__ counts, int* __restrict__ offsets,
              int* __restrict__ cursor, int N) {
    __shared__ int s_cnt[MAX_NODES_SCAN];
    __shared__ int s_ps[SCAN_T];
    const int t = threadIdx.x;
    for (int i = t; i < N; i += SCAN_T) s_cnt[i] = counts[i];
    __syncthreads();
    const int CH = (N + SCAN_T - 1) / SCAN_T;
    const int base = t * CH;
    int tsum = 0;
    for (int k = 0; k < CH; ++k) { int i = base + k; if (i < N) tsum += s_cnt[i]; }
    s_ps[t] = tsum;
    __syncthreads();
    for (int off = 1; off < SCAN_T; off <<= 1) {
        int v = (t >= off) ? s_ps[t - off] : 0;
        __syncthreads();
        s_ps[t] += v;
        __syncthreads();
    }
    int run = (t == 0) ? 0 : s_ps[t - 1];
    for (int k = 0; k < CH; ++k) {
        int i = base + k;
        if (i < N) { int c = s_cnt[i]; offsets[i] = run; cursor[i] = run; run += c; }
    }
    if (t == 0) offsets[N] = s_ps[SCAN_T - 1];
}

__global__ void csr_scatter(const int* __restrict__ recv, int* __restrict__ cursor,
                            int* __restrict__ eids, int E) {
    int e = blockIdx.x * 256 + threadIdx.x;
    if (e < E) {
        int p = atomicAdd(&cursor[recv[e]], 1);
        eids[p] = e;
    }
}

// ============================================================
// Per-node gather (no atomics, writes out directly)
// ============================================================
__global__ __launch_bounds__(NTHREADS)
void node_gather(const float* __restrict__ edge_s,
                 const float* __restrict__ edge_v,
                 const float* __restrict__ attr_s,
                 const float* __restrict__ attr_v,
                 const float* __restrict__ gate,
                 const int*   __restrict__ offsets,
                 const int*   __restrict__ eids,
                 float* __restrict__ out)
{
    __shared__ int s_ids[NTHREADS];
    const int n   = blockIdx.x;
    const int tid = threadIdx.x;
    const int start = offsets[n];
    const int end   = offsets[n + 1];
    const int i = tid - 128;

    float  acc0 = 0.0f;
    float3 acc1 = make_float3(0.0f, 0.0f, 0.0f);

    for (int base = start; base < end; base += NTHREADS) {
        const int cnt = min(NTHREADS, end - base);
        __syncthreads();
        if (tid < cnt) s_ids[tid] = eids[base + tid];
        __syncthreads();
        for (int p = 0; p < cnt; ++p) {
            const int e = s_ids[p];
            const float as  = attr_s[e];
            const float av0 = attr_v[e * 3 + 0];
            const float av1 = attr_v[e * 3 + 1];
            const float av2 = attr_v[e * 3 + 2];
            const float g   = gate[(size_t)e * 256 + tid];
            if (tid < 64) {
                acc0 = fmaf(edge_s[(size_t)e * 64 + tid] * as, g, acc0);
            } else if (tid < 128) {
                const float* ev = &edge_v[((size_t)e * 64 + (tid - 64)) * 3];
                float val = (ev[0] * av0 + ev[1] * av1 + ev[2] * av2) * INV_SQRT3f;
                acc0 = fmaf(val, g, acc0);
            } else if (i < 64) {
                float es = edge_s[(size_t)e * 64 + i];
                acc1.x = fmaf(es * av0, g, acc1.x);
                acc1.y = fmaf(es * av1, g, acc1.y);
                acc1.z = fmaf(es * av2, g, acc1.z);
            } else {
                const float* ev = &edge_v[((size_t)e * 64 + (i - 64)) * 3];
                acc1.x = fmaf(ev[0] * as, g, acc1.x);
                acc1.y = fmaf(ev[1] * as, g, acc1.y);
                acc1.z = fmaf(ev[2] * as, g, acc1.z);
            }
        }
    }

    float* orow = out + (size_t)n * 512;
    if (tid < 128) {
        orow[tid] = acc0;
    } else {
        orow[128 + 3 * i + 0] = acc1.x;
        orow[128 + 3 * i + 1] = acc1.y;
        orow[128 + 3 * i + 2] = acc1.z;
    }
}

// ============================================================
// Fallback: fused atomic kernel (used only if ws too small)
// ============================================================
__global__ __launch_bounds__(NTHREADS)
void mpconv_fused_atomic(const float* __restrict__ edge_s,
                         const float* __restrict__ edge_v,
                         const float* __restrict__ attr_s,
                         const float* __restrict__ attr_v,
                         const float* __restrict__ W1, const float* __restrict__ b1,
                         const float* __restrict__ W2, const float* __restrict__ b2,
                         const float* __restrict__ Wg, const float* __restrict__ bg,
                         const int*   __restrict__ recv,
                         float* __restrict__ out)
{
    __shared__ float s_esT[64][20];
    __shared__ float s_h1T[128][20];
    __shared__ float s_h2T[128][20];
    __shared__ float s_as[EPB];
    __shared__ float s_av[EPB][3];
    __shared__ int   s_r[EPB];

    const int tid = threadIdx.x;
    const long e0 = (long)blockIdx.x * EPB;

    for (int idx = tid; idx < EPB * 64; idx += NTHREADS) {
        int e = idx >> 6, k = idx & 63;
        s_esT[k][e] = edge_s[(e0 + e) * 64 + k];
    }
    if (tid < EPB) { s_as[tid] = attr_s[e0 + tid]; s_r[tid] = recv[e0 + tid]; }
    if (tid >= 64 && tid < 64 + EPB * 3) {
        int q = tid - 64; int e = q / 3, c = q - e * 3;
        s_av[e][c] = attr_v[(e0 + e) * 3 + c];
    }
    __syncthreads();

    const int j  = tid & 127;
    const int eg = (tid >> 7) << 3;
    {
        float acc[8];
        #pragma unroll
        for (int e = 0; e < 8; ++e) acc[e] = 0.0f;
        #pragma unroll 4
        for (int k = 0; k < 64; ++k) {
            float w  = W1[k * 128 + j];
            float4 a = *(const float4*)&s_esT[k][eg];
            float4 b = *(const float4*)&s_esT[k][eg + 4];
            acc[0] = fmaf(a.x, w, acc[0]); acc[1] = fmaf(a.y, w, acc[1]);
            acc[2] = fmaf(a.z, w, acc[2]); acc[3] = fmaf(a.w, w, acc[3]);
            acc[4] = fmaf(b.x, w, acc[4]); acc[5] = fmaf(b.y, w, acc[5]);
            acc[6] = fmaf(b.z, w, acc[6]); acc[7] = fmaf(b.w, w, acc[7]);
        }
        float bb = b1[j];
        float4 r0, r1;
        r0.x = silu_f(acc[0] + bb); r0.y = silu_f(acc[1] + bb);
        r0.z = silu_f(acc[2] + bb); r0.w = silu_f(acc[3] + bb);
        r1.x = silu_f(acc[4] + bb); r1.y = silu_f(acc[5] + bb);
        r1.z = silu_f(acc[6] + bb); r1.w = silu_f(acc[7] + bb);
        *(float4*)&s_h1T[j][eg]     = r0;
        *(float4*)&s_h1T[j][eg + 4] = r1;
    }
    __syncthreads();
    {
        float acc[8];
        #pragma unroll
        for (int e = 0; e < 8; ++e) acc[e] = 0.0f;
        #pragma unroll 4
        for (int k = 0; k < 128; ++k) {
            float w  = W2[k * 128 + j];
            float4 a = *(const float4*)&s_h1T[k][eg];
            float4 b = *(const float4*)&s_h1T[k][eg + 4];
            acc[0] = fmaf(a.x, w, acc[0]); acc[1] = fmaf(a.y, w, acc[1]);
            acc[2] = fmaf(a.z, w, acc[2]); acc[3] = fmaf(a.w, w, acc[3]);
            acc[4] = fmaf(b.x, w, acc[4]); acc[5] = fmaf(b.y, w, acc[5]);
            acc[6] = fmaf(b.z, w, acc[6]); acc[7] = fmaf(b.w, w, acc[7]);
        }
        float bb = b2[j];
        float4 r0, r1;
        r0.x = silu_f(acc[0] + bb); r0.y = silu_f(acc[1] + bb);
        r0.z = silu_f(acc[2] + bb); r0.w = silu_f(acc[3] + bb);
        r1.x = silu_f(acc[4] + bb); r1.y = silu_f(acc[5] + bb);
        r1.z = silu_f(acc[6] + bb); r1.w = silu_f(acc[7] + bb);
        *(float4*)&s_h2T[j][eg]     = r0;
        *(float4*)&s_h2T[j][eg + 4] = r1;
    }
    __syncthreads();
    float g[EPB];
    {
        float acc[16];
        #pragma unroll
        for (int e = 0; e < 16; ++e) acc[e] = 0.0f;
        #pragma unroll 2
        for (int k = 0; k < 128; ++k) {
            float w = Wg[k * 256 + tid];
            float4 a0 = *(const float4*)&s_h2T[k][0];
            float4 a1 = *(const float4*)&s_h2T[k][4];
            float4 a2 = *(const float4*)&s_h2T[k][8];
            float4 a3 = *(const float4*)&s_h2T[k][12];
            acc[0]  = fmaf(a0.x, w, acc[0]);  acc[1]  = fmaf(a0.y, w, acc[1]);
            acc[2]  = fmaf(a0.z, w, acc[2]);  acc[3]  = fmaf(a0.w, w, acc[3]);
            acc[4]  = fmaf(a1.x, w, acc[4]);  acc[5]  = fmaf(a1.y, w, acc[5]);
            acc[6]  = fmaf(a1.z, w, acc[6]);  acc[7]  = fmaf(a1.w, w, acc[7]);
            acc[8]  = fmaf(a2.x, w, acc[8]);  acc[9]  = fmaf(a2.y, w, acc[9]);
            acc[10] = fmaf(a2.z, w, acc[10]); acc[11] = fmaf(a2.w, w, acc[11]);
            acc[12] = fmaf(a3.x, w, acc[12]); acc[13] = fmaf(a3.y, w, acc[13]);
            acc[14] = fmaf(a3.z, w, acc[14]); acc[15] = fmaf(a3.w, w, acc[15]);
        }
        float bb = bg[tid];
        #pragma unroll
        for (int e = 0; e < 16; ++e) g[e] = (acc[e] + bb) * 0.25f;
    }
    if (tid < 128) {
        const int jj = tid;
        #pragma unroll 4
        for (int e = 0; e < EPB; ++e) {
            float val;
            if (jj < 64) {
                val = s_esT[jj][e] * s_as[e];
            } else {
                const float* ev = &edge_v[((e0 + e) * 64 + (jj - 64)) * 3];
                val = (ev[0] * s_av[e][0] + ev[1] * s_av[e][1] + ev[2] * s_av[e][2]) * INV_SQRT3f;
            }
            atomicAdd(&out[(long)s_r[e] * 512 + jj], val * g[e]);
        }
    } else {
        const int ii = tid - 128;
        #pragma unroll 4
        for (int e = 0; e < EPB; ++e) {
            float mx, my, mz;
            if (ii < 64) {
                float es = s_esT[ii][e];
                mx = es * s_av[e][0]; my = es * s_av[e][1]; mz = es * s_av[e][2];
            } else {
                const float* ev = &edge_v[((e0 + e) * 64 + (ii - 64)) * 3];
                float as = s_as[e];
                mx = ev[0] * as; my = ev[1] * as; mz = ev[2] * as;
            }
            float* o = &out[(long)s_r[e] * 512 + 128 + ii * 3];
            atomicAdd(o + 0, mx * g[e]);
            atomicAdd(o + 1, my * g[e]);
            atomicAdd(o + 2, mz * g[e]);
        }
    }
}

extern "C" void kernel_launch(void* const* d_in, const int* in_sizes, int n_in,
                              void* d_out, int out_size, void* d_ws, size_t ws_size,
                              hipStream_t stream) {
    const float* edge_s = (const float*)d_in[0];
    const float* edge_v = (const float*)d_in[1];
    const float* attr_s = (const float*)d_in[2];
    const float* attr_v = (const float*)d_in[3];
    const float* W1     = (const float*)d_in[4];
    const float* b1     = (const float*)d_in[5];
    const float* W2     = (const float*)d_in[6];
    const float* b2     = (const float*)d_in[7];
    const float* Wg     = (const float*)d_in[8];
    const float* bg     = (const float*)d_in[9];
    const int*   recv   = (const int*)d_in[10];

    const int E = in_sizes[0] / 64;            // 160000
    const int N = out_size / 512;              // 10000

    const size_t gate_bytes = (size_t)E * 256 * sizeof(float);
    const size_t int_count  = (size_t)N /*counts*/ + (size_t)(N + 1) /*offsets*/
                            + (size_t)N /*cursor*/ + (size_t)E /*eids*/;
    const size_t needed = gate_bytes + int_count * sizeof(int);

    if (ws_size < needed || N > MAX_NODES_SCAN) {
        // fallback: fused atomic path
        hipMemsetAsync(d_out, 0, (size_t)out_size * sizeof(float), stream);
        mpconv_fused_atomic<<<E / EPB, NTHREADS, 0, stream>>>(
            edge_s, edge_v, attr_s, attr_v, W1, b1, W2, b2, Wg, bg, recv,
            (float*)d_out);
        return;
    }

    float* gate    = (float*)d_ws;
    int*   counts  = (int*)((char*)d_ws + gate_bytes);
    int*   offsets = counts + N;
    int*   cursor  = offsets + (N + 1);
    int*   eids    = cursor + N;

    hipMemsetAsync(counts, 0, (size_t)N * sizeof(int), stream);
    csr_hist   <<<(E + 255) / 256, 256, 0, stream>>>(recv, counts, E);
    csr_scan   <<<1, SCAN_T, 0, stream>>>(counts, offsets, cursor, N);
    csr_scatter<<<(E + 255) / 256, 256, 0, stream>>>(recv, cursor, eids, E);
    mlp_gate   <<<E / EPB, NTHREADS, 0, stream>>>(edge_s, W1, b1, W2, b2, Wg, bg, gate);
    node_gather<<<N, NTHREADS, 0, stream>>>(edge_s, edge_v, attr_s, attr_v,
                                            gate, offsets, eids, (float*)d_out);
}

// Round 8
// 380.319 us; speedup vs baseline: 2.4328x; 1.6749x over previous
//
#include <hip/hip_runtime.h>
#include <math.h>

#define EPB 16
#define MEPB 32
#define NTHREADS 256
#define SCAN_T 1024
#define MAX_NODES_SCAN 10240
#define INV_SQRT3f 0.57735026918962584f
#define WFRAG_BYTES (112 * 1024)

typedef short bf16x8 __attribute__((ext_vector_type(8)));
typedef float f32x4  __attribute__((ext_vector_type(4)));

__device__ __forceinline__ float silu_f(float x) {
    return x * (1.0f / (1.0f + __expf(-x)));
}

__device__ __forceinline__ unsigned short f2bf(float f) {
    union { float f; unsigned u; } c; c.f = f;
    unsigned u = c.u + 0x7FFFu + ((c.u >> 16) & 1u);   // round-to-nearest-even
    return (unsigned short)(u >> 16);
}

// ============================================================
// Weight prep: pack W1/W2/Wg into bf16 MFMA B-fragments.
// frag(nt,kt): lane l, elem j = W[kt*32 + (l>>4)*8 + j][nt*16 + (l&15)]
// fids: [0,16)=W1 (nt*2+kt), [16,48)=W2 (nt*4+kt), [48,112)=Wg (nt*4+kt)
// ============================================================
__global__ __launch_bounds__(64)
void wprep(const float* __restrict__ W1, const float* __restrict__ W2,
           const float* __restrict__ Wg, short* __restrict__ wf) {
    const int fid = blockIdx.x;
    const int l = threadIdx.x;
    const float* W; int N, nt, kt;
    if (fid < 16)      { W = W1; N = 128; nt = fid >> 1;        kt = fid & 1; }
    else if (fid < 48) { W = W2; N = 128; nt = (fid - 16) >> 2; kt = (fid - 16) & 3; }
    else               { W = Wg; N = 256; nt = (fid - 48) >> 2; kt = (fid - 48) & 3; }
    const int col = nt * 16 + (l & 15);
    const int k0  = kt * 32 + (l >> 4) * 8;
    short* out = wf + fid * 512 + l * 8;
    #pragma unroll
    for (int j = 0; j < 8; ++j)
        out[j] = (short)f2bf(W[(k0 + j) * N + col]);
}

// ============================================================
// MFMA edge-MLP -> gate (256 f32/edge, 0.25 folded). 32 edges/block.
// ============================================================
__global__ __launch_bounds__(NTHREADS)
void mlp_gate_mfma(const float* __restrict__ edge_s,   // (E,64)
                   const float* __restrict__ b1,       // (128)
                   const float* __restrict__ b2,       // (128)
                   const float* __restrict__ bg,       // (256)
                   const short* __restrict__ wf,       // packed B-frags
                   float* __restrict__ gate_out,       // (E,256)
                   int E)
{
    __shared__ alignas(16) char h_lds[2][32 * 256];   // [buf][32 edges][128 bf16]

    const int tid = threadIdx.x;
    const int w  = tid >> 6;          // wave 0..3
    const int l  = tid & 63;
    const int lg = l >> 4;            // 0..3
    const int lc = l & 15;
    const long e0 = (long)blockIdx.x * MEPB;
    if (e0 + MEPB > E) return;

    // ---- Layer 1: A from global, B frags from wf ----
    bf16x8 a1[2][2];
    #pragma unroll
    for (int mt = 0; mt < 2; ++mt)
        #pragma unroll
        for (int kt = 0; kt < 2; ++kt) {
            const float* p = edge_s + (e0 + mt * 16 + lc) * 64 + kt * 32 + lg * 8;
            float4 x0 = *(const float4*)p;
            float4 x1 = *(const float4*)(p + 4);
            bf16x8 a;
            a[0] = (short)f2bf(x0.x); a[1] = (short)f2bf(x0.y);
            a[2] = (short)f2bf(x0.z); a[3] = (short)f2bf(x0.w);
            a[4] = (short)f2bf(x1.x); a[5] = (short)f2bf(x1.y);
            a[6] = (short)f2bf(x1.z); a[7] = (short)f2bf(x1.w);
            a1[mt][kt] = a;
        }

    {
        bf16x8 bw[2][2];
        #pragma unroll
        for (int nt = 0; nt < 2; ++nt)
            #pragma unroll
            for (int kt = 0; kt < 2; ++kt)
                bw[nt][kt] = *(const bf16x8*)(wf + ((2 * w + nt) * 2 + kt) * 512 + l * 8);

        f32x4 acc[2][2];
        #pragma unroll
        for (int mt = 0; mt < 2; ++mt)
            #pragma unroll
            for (int nt = 0; nt < 2; ++nt) {
                f32x4 c = {0.f, 0.f, 0.f, 0.f};
                #pragma unroll
                for (int kt = 0; kt < 2; ++kt)
                    c = __builtin_amdgcn_mfma_f32_16x16x32_bf16(a1[mt][kt], bw[nt][kt], c, 0, 0, 0);
                acc[mt][nt] = c;
            }

        // bias + silu -> h1 LDS (swizzled)
        #pragma unroll
        for (int nt = 0; nt < 2; ++nt) {
            float bb = b1[32 * w + nt * 16 + lc];
            int col2 = (32 * w + nt * 16 + lc) * 2;
            #pragma unroll
            for (int mt = 0; mt < 2; ++mt)
                #pragma unroll
                for (int r = 0; r < 4; ++r) {
                    int row = mt * 16 + lg * 4 + r;
                    int off = (row * 256 + col2) ^ ((row & 7) << 4);
                    *(unsigned short*)&h_lds[0][off] = f2bf(silu_f(acc[mt][nt][r] + bb));
                }
        }
    }
    __syncthreads();

    // ---- Layer 2: A from h_lds[0], K=128 ----
    {
        bf16x8 a2[2][4];
        #pragma unroll
        for (int mt = 0; mt < 2; ++mt)
            #pragma unroll
            for (int kt = 0; kt < 4; ++kt) {
                int row = mt * 16 + lc;
                int off = (row * 256 + (kt * 32 + lg * 8) * 2) ^ ((row & 7) << 4);
                a2[mt][kt] = *(const bf16x8*)&h_lds[0][off];
            }

        f32x4 acc[2][2];
        #pragma unroll
        for (int mt = 0; mt < 2; ++mt)
            #pragma unroll
            for (int nt = 0; nt < 2; ++nt) { f32x4 z = {0.f,0.f,0.f,0.f}; acc[mt][nt] = z; }

        #pragma unroll
        for (int kt = 0; kt < 4; ++kt) {
            bf16x8 bw[2];
            #pragma unroll
            for (int nt = 0; nt < 2; ++nt)
                bw[nt] = *(const bf16x8*)(wf + (16 + (2 * w + nt) * 4 + kt) * 512 + l * 8);
            #pragma unroll
            for (int mt = 0; mt < 2; ++mt)
                #pragma unroll
                for (int nt = 0; nt < 2; ++nt)
                    acc[mt][nt] = __builtin_amdgcn_mfma_f32_16x16x32_bf16(a2[mt][kt], bw[nt], acc[mt][nt], 0, 0, 0);
        }

        #pragma unroll
        for (int nt = 0; nt < 2; ++nt) {
            float bb = b2[32 * w + nt * 16 + lc];
            int col2 = (32 * w + nt * 16 + lc) * 2;
            #pragma unroll
            for (int mt = 0; mt < 2; ++mt)
                #pragma unroll
                for (int r = 0; r < 4; ++r) {
                    int row = mt * 16 + lg * 4 + r;
                    int off = (row * 256 + col2) ^ ((row & 7) << 4);
                    *(unsigned short*)&h_lds[1][off] = f2bf(silu_f(acc[mt][nt][r] + bb));
                }
        }
    }
    __syncthreads();

    // ---- Layer 3: gate = h2 @ Wg + bg, N=256 (64 cols/wave) ----
    {
        bf16x8 a3[2][4];
        #pragma unroll
        for (int mt = 0; mt < 2; ++mt)
            #pragma unroll
            for (int kt = 0; kt < 4; ++kt) {
                int row = mt * 16 + lc;
                int off = (row * 256 + (kt * 32 + lg * 8) * 2) ^ ((row & 7) << 4);
                a3[mt][kt] = *(const bf16x8*)&h_lds[1][off];
            }

        f32x4 acc[2][4];
        #pragma unroll
        for (int mt = 0; mt < 2; ++mt)
            #pragma unroll
            for (int nt = 0; nt < 4; ++nt) { f32x4 z = {0.f,0.f,0.f,0.f}; acc[mt][nt] = z; }

        #pragma unroll
        for (int kt = 0; kt < 4; ++kt) {
            bf16x8 bw[4];
            #pragma unroll
            for (int nt = 0; nt < 4; ++nt)
                bw[nt] = *(const bf16x8*)(wf + (48 + (4 * w + nt) * 4 + kt) * 512 + l * 8);
            #pragma unroll
            for (int mt = 0; mt < 2; ++mt)
                #pragma unroll
                for (int nt = 0; nt < 4; ++nt)
                    acc[mt][nt] = __builtin_amdgcn_mfma_f32_16x16x32_bf16(a3[mt][kt], bw[nt], acc[mt][nt], 0, 0, 0);
        }

        // bias + 0.25 scale, store f32 gate
        #pragma unroll
        for (int nt = 0; nt < 4; ++nt) {
            int col = 64 * w + nt * 16 + lc;
            float bb = bg[col];
            #pragma unroll
            for (int mt = 0; mt < 2; ++mt)
                #pragma unroll
                for (int r = 0; r < 4; ++r) {
                    long e = e0 + mt * 16 + lg * 4 + r;
                    gate_out[e * 256 + col] = (acc[mt][nt][r] + bb) * 0.25f;
                }
        }
    }
}

// ============================================================
// CSR build
// ============================================================
__global__ void csr_hist(const int* __restrict__ recv, int* __restrict__ counts, int E) {
    int e = blockIdx.x * 256 + threadIdx.x;
    if (e < E) atomicAdd(&counts[recv[e]], 1);
}

__global__ __launch_bounds__(SCAN_T)
void csr_scan(const int* __restrict__ counts, int* __restrict__ offsets,
              int* __restrict__ cursor, int N) {
    __shared__ int s_cnt[MAX_NODES_SCAN];
    __shared__ int s_ps[SCAN_T];
    const int t = threadIdx.x;
    for (int i = t; i < N; i += SCAN_T) s_cnt[i] = counts[i];
    __syncthreads();
    const int CH = (N + SCAN_T - 1) / SCAN_T;
    const int base = t * CH;
    int tsum = 0;
    for (int k = 0; k < CH; ++k) { int i = base + k; if (i < N) tsum += s_cnt[i]; }
    s_ps[t] = tsum;
    __syncthreads();
    for (int off = 1; off < SCAN_T; off <<= 1) {
        int v = (t >= off) ? s_ps[t - off] : 0;
        __syncthreads();
        s_ps[t] += v;
        __syncthreads();
    }
    int run = (t == 0) ? 0 : s_ps[t - 1];
    for (int k = 0; k < CH; ++k) {
        int i = base + k;
        if (i < N) { int c = s_cnt[i]; offsets[i] = run; cursor[i] = run; run += c; }
    }
    if (t == 0) offsets[N] = s_ps[SCAN_T - 1];
}

__global__ void csr_scatter(const int* __restrict__ recv, int* __restrict__ cursor,
                            int* __restrict__ eids, int E) {
    int e = blockIdx.x * 256 + threadIdx.x;
    if (e < E) {
        int p = atomicAdd(&cursor[recv[e]], 1);
        eids[p] = e;
    }
}

// ============================================================
// Per-node gather (no atomics, writes out directly)
// ============================================================
__global__ __launch_bounds__(NTHREADS)
void node_gather(const float* __restrict__ edge_s,
                 const float* __restrict__ edge_v,
                 const float* __restrict__ attr_s,
                 const float* __restrict__ attr_v,
                 const float* __restrict__ gate,
                 const int*   __restrict__ offsets,
                 const int*   __restrict__ eids,
                 float* __restrict__ out)
{
    __shared__ int s_ids[NTHREADS];
    const int n   = blockIdx.x;
    const int tid = threadIdx.x;
    const int start = offsets[n];
    const int end   = offsets[n + 1];
    const int i = tid - 128;

    float  acc0 = 0.0f;
    float3 acc1 = make_float3(0.0f, 0.0f, 0.0f);

    for (int base = start; base < end; base += NTHREADS) {
        const int cnt = min(NTHREADS, end - base);
        __syncthreads();
        if (tid < cnt) s_ids[tid] = eids[base + tid];
        __syncthreads();
        for (int p = 0; p < cnt; ++p) {
            const int e = s_ids[p];
            const float as  = attr_s[e];
            const float av0 = attr_v[e * 3 + 0];
            const float av1 = attr_v[e * 3 + 1];
            const float av2 = attr_v[e * 3 + 2];
            const float g   = gate[(size_t)e * 256 + tid];
            if (tid < 64) {
                acc0 = fmaf(edge_s[(size_t)e * 64 + tid] * as, g, acc0);
            } else if (tid < 128) {
                const float* ev = &edge_v[((size_t)e * 64 + (tid - 64)) * 3];
                float val = (ev[0] * av0 + ev[1] * av1 + ev[2] * av2) * INV_SQRT3f;
                acc0 = fmaf(val, g, acc0);
            } else if (i < 64) {
                float es = edge_s[(size_t)e * 64 + i];
                acc1.x = fmaf(es * av0, g, acc1.x);
                acc1.y = fmaf(es * av1, g, acc1.y);
                acc1.z = fmaf(es * av2, g, acc1.z);
            } else {
                const float* ev = &edge_v[((size_t)e * 64 + (i - 64)) * 3];
                acc1.x = fmaf(ev[0] * as, g, acc1.x);
                acc1.y = fmaf(ev[1] * as, g, acc1.y);
                acc1.z = fmaf(ev[2] * as, g, acc1.z);
            }
        }
    }

    float* orow = out + (size_t)n * 512;
    if (tid < 128) {
        orow[tid] = acc0;
    } else {
        orow[128 + 3 * i + 0] = acc1.x;
        orow[128 + 3 * i + 1] = acc1.y;
        orow[128 + 3 * i + 2] = acc1.z;
    }
}

// ============================================================
// Fallback: fused atomic kernel (used only if ws too small)
// ============================================================
__global__ __launch_bounds__(NTHREADS)
void mpconv_fused_atomic(const float* __restrict__ edge_s,
                         const float* __restrict__ edge_v,
                         const float* __restrict__ attr_s,
                         const float* __restrict__ attr_v,
                         const float* __restrict__ W1, const float* __restrict__ b1,
                         const float* __restrict__ W2, const float* __restrict__ b2,
                         const float* __restrict__ Wg, const float* __restrict__ bg,
                         const int*   __restrict__ recv,
                         float* __restrict__ out)
{
    __shared__ float s_esT[64][20];
    __shared__ float s_h1T[128][20];
    __shared__ float s_h2T[128][20];
    __shared__ float s_as[EPB];
    __shared__ float s_av[EPB][3];
    __shared__ int   s_r[EPB];

    const int tid = threadIdx.x;
    const long e0 = (long)blockIdx.x * EPB;

    for (int idx = tid; idx < EPB * 64; idx += NTHREADS) {
        int e = idx >> 6, k = idx & 63;
        s_esT[k][e] = edge_s[(e0 + e) * 64 + k];
    }
    if (tid < EPB) { s_as[tid] = attr_s[e0 + tid]; s_r[tid] = recv[e0 + tid]; }
    if (tid >= 64 && tid < 64 + EPB * 3) {
        int q = tid - 64; int e = q / 3, c = q - e * 3;
        s_av[e][c] = attr_v[(e0 + e) * 3 + c];
    }
    __syncthreads();

    const int j  = tid & 127;
    const int eg = (tid >> 7) << 3;
    {
        float acc[8];
        #pragma unroll
        for (int e = 0; e < 8; ++e) acc[e] = 0.0f;
        #pragma unroll 4
        for (int k = 0; k < 64; ++k) {
            float w  = W1[k * 128 + j];
            float4 a = *(const float4*)&s_esT[k][eg];
            float4 b = *(const float4*)&s_esT[k][eg + 4];
            acc[0] = fmaf(a.x, w, acc[0]); acc[1] = fmaf(a.y, w, acc[1]);
            acc[2] = fmaf(a.z, w, acc[2]); acc[3] = fmaf(a.w, w, acc[3]);
            acc[4] = fmaf(b.x, w, acc[4]); acc[5] = fmaf(b.y, w, acc[5]);
            acc[6] = fmaf(b.z, w, acc[6]); acc[7] = fmaf(b.w, w, acc[7]);
        }
        float bb = b1[j];
        float4 r0, r1;
        r0.x = silu_f(acc[0] + bb); r0.y = silu_f(acc[1] + bb);
        r0.z = silu_f(acc[2] + bb); r0.w = silu_f(acc[3] + bb);
        r1.x = silu_f(acc[4] + bb); r1.y = silu_f(acc[5] + bb);
        r1.z = silu_f(acc[6] + bb); r1.w = silu_f(acc[7] + bb);
        *(float4*)&s_h1T[j][eg]     = r0;
        *(float4*)&s_h1T[j][eg + 4] = r1;
    }
    __syncthreads();
    {
        float acc[8];
        #pragma unroll
        for (int e = 0; e < 8; ++e) acc[e] = 0.0f;
        #pragma unroll 4
        for (int k = 0; k < 128; ++k) {
            float w  = W2[k * 128 + j];
            float4 a = *(const float4*)&s_h1T[k][eg];
            float4 b = *(const float4*)&s_h1T[k][eg + 4];
            acc[0] = fmaf(a.x, w, acc[0]); acc[1] = fmaf(a.y, w, acc[1]);
            acc[2] = fmaf(a.z, w, acc[2]); acc[3] = fmaf(a.w, w, acc[3]);
            acc[4] = fmaf(b.x, w, acc[4]); acc[5] = fmaf(b.y, w, acc[5]);
            acc[6] = fmaf(b.z, w, acc[6]); acc[7] = fmaf(b.w, w, acc[7]);
        }
        float bb = b2[j];
        float4 r0, r1;
        r0.x = silu_f(acc[0] + bb); r0.y = silu_f(acc[1] + bb);
        r0.z = silu_f(acc[2] + bb); r0.w = silu_f(acc[3] + bb);
        r1.x = silu_f(acc[4] + bb); r1.y = silu_f(acc[5] + bb);
        r1.z = silu_f(acc[6] + bb); r1.w = silu_f(acc[7] + bb);
        *(float4*)&s_h2T[j][eg]     = r0;
        *(float4*)&s_h2T[j][eg + 4] = r1;
    }
    __syncthreads();
    float g[EPB];
    {
        float acc[16];
        #pragma unroll
        for (int e = 0; e < 16; ++e) acc[e] = 0.0f;
        #pragma unroll 2
        for (int k = 0; k < 128; ++k) {
            float w = Wg[k * 256 + tid];
            float4 a0 = *(const float4*)&s_h2T[k][0];
            float4 a1 = *(const float4*)&s_h2T[k][4];
            float4 a2 = *(const float4*)&s_h2T[k][8];
            float4 a3 = *(const float4*)&s_h2T[k][12];
            acc[0]  = fmaf(a0.x, w, acc[0]);  acc[1]  = fmaf(a0.y, w, acc[1]);
            acc[2]  = fmaf(a0.z, w, acc[2]);  acc[3]  = fmaf(a0.w, w, acc[3]);
            acc[4]  = fmaf(a1.x, w, acc[4]);  acc[5]  = fmaf(a1.y, w, acc[5]);
            acc[6]  = fmaf(a1.z, w, acc[6]);  acc[7]  = fmaf(a1.w, w, acc[7]);
            acc[8]  = fmaf(a2.x, w, acc[8]);  acc[9]  = fmaf(a2.y, w, acc[9]);
            acc[10] = fmaf(a2.z, w, acc[10]); acc[11] = fmaf(a2.w, w, acc[11]);
            acc[12] = fmaf(a3.x, w, acc[12]); acc[13] = fmaf(a3.y, w, acc[13]);
            acc[14] = fmaf(a3.z, w, acc[14]); acc[15] = fmaf(a3.w, w, acc[15]);
        }
        float bb = bg[tid];
        #pragma unroll
        for (int e = 0; e < 16; ++e) g[e] = (acc[e] + bb) * 0.25f;
    }
    if (tid < 128) {
        const int jj = tid;
        #pragma unroll 4
        for (int e = 0; e < EPB; ++e) {
            float val;
            if (jj < 64) {
                val = s_esT[jj][e] * s_as[e];
            } else {
                const float* ev = &edge_v[((e0 + e) * 64 + (jj - 64)) * 3];
                val = (ev[0] * s_av[e][0] + ev[1] * s_av[e][1] + ev[2] * s_av[e][2]) * INV_SQRT3f;
            }
            atomicAdd(&out[(long)s_r[e] * 512 + jj], val * g[e]);
        }
    } else {
        const int ii = tid - 128;
        #pragma unroll 4
        for (int e = 0; e < EPB; ++e) {
            float mx, my, mz;
            if (ii < 64) {
                float es = s_esT[ii][e];
                mx = es * s_av[e][0]; my = es * s_av[e][1]; mz = es * s_av[e][2];
            } else {
                const float* ev = &edge_v[((e0 + e) * 64 + (ii - 64)) * 3];
                float as = s_as[e];
                mx = ev[0] * as; my = ev[1] * as; mz = ev[2] * as;
            }
            float* o = &out[(long)s_r[e] * 512 + 128 + ii * 3];
            atomicAdd(o + 0, mx * g[e]);
            atomicAdd(o + 1, my * g[e]);
            atomicAdd(o + 2, mz * g[e]);
        }
    }
}

extern "C" void kernel_launch(void* const* d_in, const int* in_sizes, int n_in,
                              void* d_out, int out_size, void* d_ws, size_t ws_size,
                              hipStream_t stream) {
    const float* edge_s = (const float*)d_in[0];
    const float* edge_v = (const float*)d_in[1];
    const float* attr_s = (const float*)d_in[2];
    const float* attr_v = (const float*)d_in[3];
    const float* W1     = (const float*)d_in[4];
    const float* b1     = (const float*)d_in[5];
    const float* W2     = (const float*)d_in[6];
    const float* b2     = (const float*)d_in[7];
    const float* Wg     = (const float*)d_in[8];
    const float* bg     = (const float*)d_in[9];
    const int*   recv   = (const int*)d_in[10];

    const int E = in_sizes[0] / 64;            // 160000
    const int N = out_size / 512;              // 10000

    const size_t gate_bytes = (size_t)E * 256 * sizeof(float);
    const size_t int_count  = (size_t)N + (size_t)(N + 1) + (size_t)N + (size_t)E;
    const size_t needed = gate_bytes + WFRAG_BYTES + int_count * sizeof(int);

    if (ws_size < needed || N > MAX_NODES_SCAN || (E % MEPB) != 0) {
        // fallback: fused atomic path
        hipMemsetAsync(d_out, 0, (size_t)out_size * sizeof(float), stream);
        mpconv_fused_atomic<<<(E + EPB - 1) / EPB, NTHREADS, 0, stream>>>(
            edge_s, edge_v, attr_s, attr_v, W1, b1, W2, b2, Wg, bg, recv,
            (float*)d_out);
        return;
    }

    float* gate    = (float*)d_ws;
    short* wfrags  = (short*)((char*)d_ws + gate_bytes);
    int*   counts  = (int*)((char*)d_ws + gate_bytes + WFRAG_BYTES);
    int*   offsets = counts + N;
    int*   cursor  = offsets + (N + 1);
    int*   eids    = cursor + N;

    hipMemsetAsync(counts, 0, (size_t)N * sizeof(int), stream);
    wprep      <<<112, 64, 0, stream>>>(W1, W2, Wg, wfrags);
    csr_hist   <<<(E + 255) / 256, 256, 0, stream>>>(recv, counts, E);
    csr_scan   <<<1, SCAN_T, 0, stream>>>(counts, offsets, cursor, N);
    csr_scatter<<<(E + 255) / 256, 256, 0, stream>>>(recv, cursor, eids, E);
    mlp_gate_mfma<<<E / MEPB, NTHREADS, 0, stream>>>(edge_s, b1, b2, bg,
                                                     wfrags, gate, E);
    node_gather<<<N, NTHREADS, 0, stream>>>(edge_s, edge_v, attr_s, attr_v,
                                            gate, offsets, eids, (float*)d_out);
}

// Round 9
// 374.942 us; speedup vs baseline: 2.4677x; 1.0143x over previous
//
#include <hip/hip_runtime.h>
#include <math.h>

#define EPB 16
#define MEPB 32
#define NTHREADS 256
#define SCAN_T 1024
#define MAX_NODES_SCAN 10240
#define INV_SQRT3f 0.57735026918962584f
#define WFRAG_BYTES (112 * 1024)

typedef short bf16x8 __attribute__((ext_vector_type(8)));
typedef float f32x4  __attribute__((ext_vector_type(4)));

__device__ __forceinline__ float silu_f(float x) {
    return x * (1.0f / (1.0f + __expf(-x)));
}

__device__ __forceinline__ unsigned short f2bf(float f) {
    union { float f; unsigned u; } c; c.f = f;
    unsigned u = c.u + 0x7FFFu + ((c.u >> 16) & 1u);   // round-to-nearest-even
    return (unsigned short)(u >> 16);
}

__device__ __forceinline__ float bf2f(unsigned short h) {
    union { unsigned u; float f; } c; c.u = ((unsigned)h) << 16; return c.f;
}

// ============================================================
// Weight prep: pack W1/W2/Wg into bf16 MFMA B-fragments.
// frag(nt,kt): lane l, elem j = W[kt*32 + (l>>4)*8 + j][nt*16 + (l&15)]
// fids: [0,16)=W1 (nt*2+kt), [16,48)=W2 (nt*4+kt), [48,112)=Wg (nt*4+kt)
// ============================================================
__global__ __launch_bounds__(64)
void wprep(const float* __restrict__ W1, const float* __restrict__ W2,
           const float* __restrict__ Wg, short* __restrict__ wf) {
    const int fid = blockIdx.x;
    const int l = threadIdx.x;
    const float* W; int N, nt, kt;
    if (fid < 16)      { W = W1; N = 128; nt = fid >> 1;        kt = fid & 1; }
    else if (fid < 48) { W = W2; N = 128; nt = (fid - 16) >> 2; kt = (fid - 16) & 3; }
    else               { W = Wg; N = 256; nt = (fid - 48) >> 2; kt = (fid - 48) & 3; }
    const int col = nt * 16 + (l & 15);
    const int k0  = kt * 32 + (l >> 4) * 8;
    short* out = wf + fid * 512 + l * 8;
    #pragma unroll
    for (int j = 0; j < 8; ++j)
        out[j] = (short)f2bf(W[(k0 + j) * N + col]);
}

// ============================================================
// MFMA edge-MLP -> gate (256 bf16/edge, 0.25 folded). 32 edges/block.
// ============================================================
__global__ __launch_bounds__(NTHREADS)
void mlp_gate_mfma(const float* __restrict__ edge_s,   // (E,64)
                   const float* __restrict__ b1,       // (128)
                   const float* __restrict__ b2,       // (128)
                   const float* __restrict__ bg,       // (256)
                   const short* __restrict__ wf,       // packed B-frags
                   unsigned short* __restrict__ gate_out, // (E,256) bf16
                   int E)
{
    __shared__ alignas(16) char h_lds[2][32 * 256];   // [buf][32 edges][128 bf16]

    const int tid = threadIdx.x;
    const int w  = tid >> 6;          // wave 0..3
    const int l  = tid & 63;
    const int lg = l >> 4;            // 0..3
    const int lc = l & 15;
    const long e0 = (long)blockIdx.x * MEPB;
    if (e0 + MEPB > E) return;

    // ---- Layer 1: A from global, B frags from wf ----
    bf16x8 a1[2][2];
    #pragma unroll
    for (int mt = 0; mt < 2; ++mt)
        #pragma unroll
        for (int kt = 0; kt < 2; ++kt) {
            const float* p = edge_s + (e0 + mt * 16 + lc) * 64 + kt * 32 + lg * 8;
            float4 x0 = *(const float4*)p;
            float4 x1 = *(const float4*)(p + 4);
            bf16x8 a;
            a[0] = (short)f2bf(x0.x); a[1] = (short)f2bf(x0.y);
            a[2] = (short)f2bf(x0.z); a[3] = (short)f2bf(x0.w);
            a[4] = (short)f2bf(x1.x); a[5] = (short)f2bf(x1.y);
            a[6] = (short)f2bf(x1.z); a[7] = (short)f2bf(x1.w);
            a1[mt][kt] = a;
        }

    {
        bf16x8 bw[2][2];
        #pragma unroll
        for (int nt = 0; nt < 2; ++nt)
            #pragma unroll
            for (int kt = 0; kt < 2; ++kt)
                bw[nt][kt] = *(const bf16x8*)(wf + ((2 * w + nt) * 2 + kt) * 512 + l * 8);

        f32x4 acc[2][2];
        #pragma unroll
        for (int mt = 0; mt < 2; ++mt)
            #pragma unroll
            for (int nt = 0; nt < 2; ++nt) {
                f32x4 c = {0.f, 0.f, 0.f, 0.f};
                #pragma unroll
                for (int kt = 0; kt < 2; ++kt)
                    c = __builtin_amdgcn_mfma_f32_16x16x32_bf16(a1[mt][kt], bw[nt][kt], c, 0, 0, 0);
                acc[mt][nt] = c;
            }

        // bias + silu -> h1 LDS (swizzled)
        #pragma unroll
        for (int nt = 0; nt < 2; ++nt) {
            float bb = b1[32 * w + nt * 16 + lc];
            int col2 = (32 * w + nt * 16 + lc) * 2;
            #pragma unroll
            for (int mt = 0; mt < 2; ++mt)
                #pragma unroll
                for (int r = 0; r < 4; ++r) {
                    int row = mt * 16 + lg * 4 + r;
                    int off = (row * 256 + col2) ^ ((row & 7) << 4);
                    *(unsigned short*)&h_lds[0][off] = f2bf(silu_f(acc[mt][nt][r] + bb));
                }
        }
    }
    __syncthreads();

    // ---- Layer 2: A from h_lds[0], K=128 ----
    {
        bf16x8 a2[2][4];
        #pragma unroll
        for (int mt = 0; mt < 2; ++mt)
            #pragma unroll
            for (int kt = 0; kt < 4; ++kt) {
                int row = mt * 16 + lc;
                int off = (row * 256 + (kt * 32 + lg * 8) * 2) ^ ((row & 7) << 4);
                a2[mt][kt] = *(const bf16x8*)&h_lds[0][off];
            }

        f32x4 acc[2][2];
        #pragma unroll
        for (int mt = 0; mt < 2; ++mt)
            #pragma unroll
            for (int nt = 0; nt < 2; ++nt) { f32x4 z = {0.f,0.f,0.f,0.f}; acc[mt][nt] = z; }

        #pragma unroll
        for (int kt = 0; kt < 4; ++kt) {
            bf16x8 bw[2];
            #pragma unroll
            for (int nt = 0; nt < 2; ++nt)
                bw[nt] = *(const bf16x8*)(wf + (16 + (2 * w + nt) * 4 + kt) * 512 + l * 8);
            #pragma unroll
            for (int mt = 0; mt < 2; ++mt)
                #pragma unroll
                for (int nt = 0; nt < 2; ++nt)
                    acc[mt][nt] = __builtin_amdgcn_mfma_f32_16x16x32_bf16(a2[mt][kt], bw[nt], acc[mt][nt], 0, 0, 0);
        }

        #pragma unroll
        for (int nt = 0; nt < 2; ++nt) {
            float bb = b2[32 * w + nt * 16 + lc];
            int col2 = (32 * w + nt * 16 + lc) * 2;
            #pragma unroll
            for (int mt = 0; mt < 2; ++mt)
                #pragma unroll
                for (int r = 0; r < 4; ++r) {
                    int row = mt * 16 + lg * 4 + r;
                    int off = (row * 256 + col2) ^ ((row & 7) << 4);
                    *(unsigned short*)&h_lds[1][off] = f2bf(silu_f(acc[mt][nt][r] + bb));
                }
        }
    }
    __syncthreads();

    // ---- Layer 3: gate = h2 @ Wg + bg, N=256 (64 cols/wave) ----
    {
        bf16x8 a3[2][4];
        #pragma unroll
        for (int mt = 0; mt < 2; ++mt)
            #pragma unroll
            for (int kt = 0; kt < 4; ++kt) {
                int row = mt * 16 + lc;
                int off = (row * 256 + (kt * 32 + lg * 8) * 2) ^ ((row & 7) << 4);
                a3[mt][kt] = *(const bf16x8*)&h_lds[1][off];
            }

        f32x4 acc[2][4];
        #pragma unroll
        for (int mt = 0; mt < 2; ++mt)
            #pragma unroll
            for (int nt = 0; nt < 4; ++nt) { f32x4 z = {0.f,0.f,0.f,0.f}; acc[mt][nt] = z; }

        #pragma unroll
        for (int kt = 0; kt < 4; ++kt) {
            bf16x8 bw[4];
            #pragma unroll
            for (int nt = 0; nt < 4; ++nt)
                bw[nt] = *(const bf16x8*)(wf + (48 + (4 * w + nt) * 4 + kt) * 512 + l * 8);
            #pragma unroll
            for (int mt = 0; mt < 2; ++mt)
                #pragma unroll
                for (int nt = 0; nt < 4; ++nt)
                    acc[mt][nt] = __builtin_amdgcn_mfma_f32_16x16x32_bf16(a3[mt][kt], bw[nt], acc[mt][nt], 0, 0, 0);
        }

        // bias + 0.25 scale, store bf16 gate
        #pragma unroll
        for (int nt = 0; nt < 4; ++nt) {
            int col = 64 * w + nt * 16 + lc;
            float bb = bg[col];
            #pragma unroll
            for (int mt = 0; mt < 2; ++mt)
                #pragma unroll
                for (int r = 0; r < 4; ++r) {
                    long e = e0 + mt * 16 + lg * 4 + r;
                    gate_out[e * 256 + col] = f2bf((acc[mt][nt][r] + bb) * 0.25f);
                }
        }
    }
}

// ============================================================
// CSR build
// ============================================================
__global__ void csr_hist(const int* __restrict__ recv, int* __restrict__ counts, int E) {
    int e = blockIdx.x * 256 + threadIdx.x;
    if (e < E) atomicAdd(&counts[recv[e]], 1);
}

__global__ __launch_bounds__(SCAN_T)
void csr_scan(const int* __restrict__ counts, int* __restrict__ offsets,
              int* __restrict__ cursor, int N) {
    __shared__ int s_cnt[MAX_NODES_SCAN];
    __shared__ int s_ps[SCAN_T];
    const int t = threadIdx.x;
    for (int i = t; i < N; i += SCAN_T) s_cnt[i] = counts[i];
    __syncthreads();
    const int CH = (N + SCAN_T - 1) / SCAN_T;
    const int base = t * CH;
    int tsum = 0;
    for (int k = 0; k < CH; ++k) { int i = base + k; if (i < N) tsum += s_cnt[i]; }
    s_ps[t] = tsum;
    __syncthreads();
    for (int off = 1; off < SCAN_T; off <<= 1) {
        int v = (t >= off) ? s_ps[t - off] : 0;
        __syncthreads();
        s_ps[t] += v;
        __syncthreads();
    }
    int run = (t == 0) ? 0 : s_ps[t - 1];
    for (int k = 0; k < CH; ++k) {
        int i = base + k;
        if (i < N) { int c = s_cnt[i]; offsets[i] = run; cursor[i] = run; run += c; }
    }
    if (t == 0) offsets[N] = s_ps[SCAN_T - 1];
}

__global__ void csr_scatter(const int* __restrict__ recv, int* __restrict__ cursor,
                            int* __restrict__ eids, int E) {
    int e = blockIdx.x * 256 + threadIdx.x;
    if (e < E) {
        int p = atomicAdd(&cursor[recv[e]], 1);
        eids[p] = e;
    }
}

// ============================================================
// Per-node gather: wave-class split, 8-edge load batching (MLP),
// bf16 gate. No atomics; writes out exactly once.
// ============================================================
__global__ __launch_bounds__(NTHREADS)
void node_gather(const float* __restrict__ edge_s,
                 const float* __restrict__ edge_v,
                 const float* __restrict__ attr_s,
                 const float* __restrict__ attr_v,
                 const unsigned short* __restrict__ gate,
                 const int*   __restrict__ offsets,
                 const int*   __restrict__ eids,
                 float* __restrict__ out)
{
    __shared__ int s_ids[NTHREADS];
    const int n    = blockIdx.x;
    const int tid  = threadIdx.x;
    const int w    = tid >> 6;        // wave class 0..3 (uniform per wave)
    const int lane = tid & 63;
    const int start = offsets[n];
    const int end   = offsets[n + 1];

    float  acc0 = 0.0f;
    float3 acc1 = make_float3(0.0f, 0.0f, 0.0f);

    for (int base = start; base < end; base += NTHREADS) {
        const int cnt = min(NTHREADS, end - base);
        __syncthreads();
        if (tid < cnt) s_ids[tid] = eids[base + tid];
        __syncthreads();

        for (int p = 0; p < cnt; p += 8) {
            const int m = min(8, cnt - p);   // uniform across block
            float gv[8];
            if (w == 0) {
                // m0[:64] = edge_s * attr_s
                float mv[8];
                #pragma unroll
                for (int q = 0; q < 8; ++q) {
                    if (q < m) {
                        const int e = s_ids[p + q];
                        gv[q] = bf2f(gate[(size_t)e * 256 + tid]);
                        mv[q] = edge_s[(size_t)e * 64 + lane] * attr_s[e];
                    } else { gv[q] = 0.0f; mv[q] = 0.0f; }
                }
                #pragma unroll
                for (int q = 0; q < 8; ++q) acc0 = fmaf(mv[q], gv[q], acc0);
            } else if (w == 1) {
                // m0[64:] = (edge_v . attr_v) * inv_sqrt3
                float mv[8];
                #pragma unroll
                for (int q = 0; q < 8; ++q) {
                    if (q < m) {
                        const int e = s_ids[p + q];
                        gv[q] = bf2f(gate[(size_t)e * 256 + tid]);
                        const float* ev = &edge_v[((size_t)e * 64 + lane) * 3];
                        mv[q] = (ev[0] * attr_v[e * 3 + 0] + ev[1] * attr_v[e * 3 + 1]
                               + ev[2] * attr_v[e * 3 + 2]) * INV_SQRT3f;
                    } else { gv[q] = 0.0f; mv[q] = 0.0f; }
                }
                #pragma unroll
                for (int q = 0; q < 8; ++q) acc0 = fmaf(mv[q], gv[q], acc0);
            } else if (w == 2) {
                // m1 rows 0..63: edge_s[i] * attr_v
                float mx[8], my[8], mz[8];
                #pragma unroll
                for (int q = 0; q < 8; ++q) {
                    if (q < m) {
                        const int e = s_ids[p + q];
                        gv[q] = bf2f(gate[(size_t)e * 256 + tid]);
                        const float es = edge_s[(size_t)e * 64 + lane];
                        mx[q] = es * attr_v[e * 3 + 0];
                        my[q] = es * attr_v[e * 3 + 1];
                        mz[q] = es * attr_v[e * 3 + 2];
                    } else { gv[q] = 0.0f; mx[q] = my[q] = mz[q] = 0.0f; }
                }
                #pragma unroll
                for (int q = 0; q < 8; ++q) {
                    acc1.x = fmaf(mx[q], gv[q], acc1.x);
                    acc1.y = fmaf(my[q], gv[q], acc1.y);
                    acc1.z = fmaf(mz[q], gv[q], acc1.z);
                }
            } else {
                // m1 rows 64..127: edge_v[i-64] * attr_s
                float mx[8], my[8], mz[8];
                #pragma unroll
                for (int q = 0; q < 8; ++q) {
                    if (q < m) {
                        const int e = s_ids[p + q];
                        gv[q] = bf2f(gate[(size_t)e * 256 + tid]);
                        const float* ev = &edge_v[((size_t)e * 64 + lane) * 3];
                        const float as = attr_s[e];
                        mx[q] = ev[0] * as; my[q] = ev[1] * as; mz[q] = ev[2] * as;
                    } else { gv[q] = 0.0f; mx[q] = my[q] = mz[q] = 0.0f; }
                }
                #pragma unroll
                for (int q = 0; q < 8; ++q) {
                    acc1.x = fmaf(mx[q], gv[q], acc1.x);
                    acc1.y = fmaf(my[q], gv[q], acc1.y);
                    acc1.z = fmaf(mz[q], gv[q], acc1.z);
                }
            }
        }
    }

    float* orow = out + (size_t)n * 512;
    if (tid < 128) {
        orow[tid] = acc0;
    } else {
        const int i = tid - 128;
        orow[128 + 3 * i + 0] = acc1.x;
        orow[128 + 3 * i + 1] = acc1.y;
        orow[128 + 3 * i + 2] = acc1.z;
    }
}

// ============================================================
// Fallback: fused atomic kernel (used only if ws too small)
// ============================================================
__global__ __launch_bounds__(NTHREADS)
void mpconv_fused_atomic(const float* __restrict__ edge_s,
                         const float* __restrict__ edge_v,
                         const float* __restrict__ attr_s,
                         const float* __restrict__ attr_v,
                         const float* __restrict__ W1, const float* __restrict__ b1,
                         const float* __restrict__ W2, const float* __restrict__ b2,
                         const float* __restrict__ Wg, const float* __restrict__ bg,
                         const int*   __restrict__ recv,
                         float* __restrict__ out)
{
    __shared__ float s_esT[64][20];
    __shared__ float s_h1T[128][20];
    __shared__ float s_h2T[128][20];
    __shared__ float s_as[EPB];
    __shared__ float s_av[EPB][3];
    __shared__ int   s_r[EPB];

    const int tid = threadIdx.x;
    const long e0 = (long)blockIdx.x * EPB;

    for (int idx = tid; idx < EPB * 64; idx += NTHREADS) {
        int e = idx >> 6, k = idx & 63;
        s_esT[k][e] = edge_s[(e0 + e) * 64 + k];
    }
    if (tid < EPB) { s_as[tid] = attr_s[e0 + tid]; s_r[tid] = recv[e0 + tid]; }
    if (tid >= 64 && tid < 64 + EPB * 3) {
        int q = tid - 64; int e = q / 3, c = q - e * 3;
        s_av[e][c] = attr_v[(e0 + e) * 3 + c];
    }
    __syncthreads();

    const int j  = tid & 127;
    const int eg = (tid >> 7) << 3;
    {
        float acc[8];
        #pragma unroll
        for (int e = 0; e < 8; ++e) acc[e] = 0.0f;
        #pragma unroll 4
        for (int k = 0; k < 64; ++k) {
            float w  = W1[k * 128 + j];
            float4 a = *(const float4*)&s_esT[k][eg];
            float4 b = *(const float4*)&s_esT[k][eg + 4];
            acc[0] = fmaf(a.x, w, acc[0]); acc[1] = fmaf(a.y, w, acc[1]);
            acc[2] = fmaf(a.z, w, acc[2]); acc[3] = fmaf(a.w, w, acc[3]);
            acc[4] = fmaf(b.x, w, acc[4]); acc[5] = fmaf(b.y, w, acc[5]);
            acc[6] = fmaf(b.z, w, acc[6]); acc[7] = fmaf(b.w, w, acc[7]);
        }
        float bb = b1[j];
        float4 r0, r1;
        r0.x = silu_f(acc[0] + bb); r0.y = silu_f(acc[1] + bb);
        r0.z = silu_f(acc[2] + bb); r0.w = silu_f(acc[3] + bb);
        r1.x = silu_f(acc[4] + bb); r1.y = silu_f(acc[5] + bb);
        r1.z = silu_f(acc[6] + bb); r1.w = silu_f(acc[7] + bb);
        *(float4*)&s_h1T[j][eg]     = r0;
        *(float4*)&s_h1T[j][eg + 4] = r1;
    }
    __syncthreads();
    {
        float acc[8];
        #pragma unroll
        for (int e = 0; e < 8; ++e) acc[e] = 0.0f;
        #pragma unroll 4
        for (int k = 0; k < 128; ++k) {
            float w  = W2[k * 128 + j];
            float4 a = *(const float4*)&s_h1T[k][eg];
            float4 b = *(const float4*)&s_h1T[k][eg + 4];
            acc[0] = fmaf(a.x, w, acc[0]); acc[1] = fmaf(a.y, w, acc[1]);
            acc[2] = fmaf(a.z, w, acc[2]); acc[3] = fmaf(a.w, w, acc[3]);
            acc[4] = fmaf(b.x, w, acc[4]); acc[5] = fmaf(b.y, w, acc[5]);
            acc[6] = fmaf(b.z, w, acc[6]); acc[7] = fmaf(b.w, w, acc[7]);
        }
        float bb = b2[j];
        float4 r0, r1;
        r0.x = silu_f(acc[0] + bb); r0.y = silu_f(acc[1] + bb);
        r0.z = silu_f(acc[2] + bb); r0.w = silu_f(acc[3] + bb);
        r1.x = silu_f(acc[4] + bb); r1.y = silu_f(acc[5] + bb);
        r1.z = silu_f(acc[6] + bb); r1.w = silu_f(acc[7] + bb);
        *(float4*)&s_h2T[j][eg]     = r0;
        *(float4*)&s_h2T[j][eg + 4] = r1;
    }
    __syncthreads();
    float g[EPB];
    {
        float acc[16];
        #pragma unroll
        for (int e = 0; e < 16; ++e) acc[e] = 0.0f;
        #pragma unroll 2
        for (int k = 0; k < 128; ++k) {
            float w = Wg[k * 256 + tid];
            float4 a0 = *(const float4*)&s_h2T[k][0];
            float4 a1 = *(const float4*)&s_h2T[k][4];
            float4 a2 = *(const float4*)&s_h2T[k][8];
            float4 a3 = *(const float4*)&s_h2T[k][12];
            acc[0]  = fmaf(a0.x, w, acc[0]);  acc[1]  = fmaf(a0.y, w, acc[1]);
            acc[2]  = fmaf(a0.z, w, acc[2]);  acc[3]  = fmaf(a0.w, w, acc[3]);
            acc[4]  = fmaf(a1.x, w, acc[4]);  acc[5]  = fmaf(a1.y, w, acc[5]);
            acc[6]  = fmaf(a1.z, w, acc[6]);  acc[7]  = fmaf(a1.w, w, acc[7]);
            acc[8]  = fmaf(a2.x, w, acc[8]);  acc[9]  = fmaf(a2.y, w, acc[9]);
            acc[10] = fmaf(a2.z, w, acc[10]); acc[11] = fmaf(a2.w, w, acc[11]);
            acc[12] = fmaf(a3.x, w, acc[12]); acc[13] = fmaf(a3.y, w, acc[13]);
            acc[14] = fmaf(a3.z, w, acc[14]); acc[15] = fmaf(a3.w, w, acc[15]);
        }
        float bb = bg[tid];
        #pragma unroll
        for (int e = 0; e < 16; ++e) g[e] = (acc[e] + bb) * 0.25f;
    }
    if (tid < 128) {
        const int jj = tid;
        #pragma unroll 4
        for (int e = 0; e < EPB; ++e) {
            float val;
            if (jj < 64) {
                val = s_esT[jj][e] * s_as[e];
            } else {
                const float* ev = &edge_v[((e0 + e) * 64 + (jj - 64)) * 3];
                val = (ev[0] * s_av[e][0] + ev[1] * s_av[e][1] + ev[2] * s_av[e][2]) * INV_SQRT3f;
            }
            atomicAdd(&out[(long)s_r[e] * 512 + jj], val * g[e]);
        }
    } else {
        const int ii = tid - 128;
        #pragma unroll 4
        for (int e = 0; e < EPB; ++e) {
            float mx, my, mz;
            if (ii < 64) {
                float es = s_esT[ii][e];
                mx = es * s_av[e][0]; my = es * s_av[e][1]; mz = es * s_av[e][2];
            } else {
                const float* ev = &edge_v[((e0 + e) * 64 + (ii - 64)) * 3];
                float as = s_as[e];
                mx = ev[0] * as; my = ev[1] * as; mz = ev[2] * as;
            }
            float* o = &out[(long)s_r[e] * 512 + 128 + ii * 3];
            atomicAdd(o + 0, mx * g[e]);
            atomicAdd(o + 1, my * g[e]);
            atomicAdd(o + 2, mz * g[e]);
        }
    }
}

extern "C" void kernel_launch(void* const* d_in, const int* in_sizes, int n_in,
                              void* d_out, int out_size, void* d_ws, size_t ws_size,
                              hipStream_t stream) {
    const float* edge_s = (const float*)d_in[0];
    const float* edge_v = (const float*)d_in[1];
    const float* attr_s = (const float*)d_in[2];
    const float* attr_v = (const float*)d_in[3];
    const float* W1     = (const float*)d_in[4];
    const float* b1     = (const float*)d_in[5];
    const float* W2     = (const float*)d_in[6];
    const float* b2     = (const float*)d_in[7];
    const float* Wg     = (const float*)d_in[8];
    const float* bg     = (const float*)d_in[9];
    const int*   recv   = (const int*)d_in[10];

    const int E = in_sizes[0] / 64;            // 160000
    const int N = out_size / 512;              // 10000

    const size_t gate_bytes = (size_t)E * 256 * sizeof(unsigned short);  // bf16 gate
    const size_t int_count  = (size_t)N + (size_t)(N + 1) + (size_t)N + (size_t)E;
    const size_t needed = gate_bytes + WFRAG_BYTES + int_count * sizeof(int);

    if (ws_size < needed || N > MAX_NODES_SCAN || (E % MEPB) != 0) {
        // fallback: fused atomic path
        hipMemsetAsync(d_out, 0, (size_t)out_size * sizeof(float), stream);
        mpconv_fused_atomic<<<(E + EPB - 1) / EPB, NTHREADS, 0, stream>>>(
            edge_s, edge_v, attr_s, attr_v, W1, b1, W2, b2, Wg, bg, recv,
            (float*)d_out);
        return;
    }

    unsigned short* gate = (unsigned short*)d_ws;
    short* wfrags  = (short*)((char*)d_ws + gate_bytes);
    int*   counts  = (int*)((char*)d_ws + gate_bytes + WFRAG_BYTES);
    int*   offsets = counts + N;
    int*   cursor  = offsets + (N + 1);
    int*   eids    = cursor + N;

    hipMemsetAsync(counts, 0, (size_t)N * sizeof(int), stream);
    wprep      <<<112, 64, 0, stream>>>(W1, W2, Wg, wfrags);
    csr_hist   <<<(E + 255) / 256, 256, 0, stream>>>(recv, counts, E);
    csr_scan   <<<1, SCAN_T, 0, stream>>>(counts, offsets, cursor, N);
    csr_scatter<<<(E + 255) / 256, 256, 0, stream>>>(recv, cursor, eids, E);
    mlp_gate_mfma<<<E / MEPB, NTHREADS, 0, stream>>>(edge_s, b1, b2, bg,
                                                     wfrags, gate, E);
    node_gather<<<N, NTHREADS, 0, stream>>>(edge_s, edge_v, attr_s, attr_v,
                                            gate, offsets, eids, (float*)d_out);
}